// Round 5
// baseline (49.947 us; speedup 1.0000x reference)
//
#include <hip/hip_runtime.h>

// Problem: B=64, C=3, S=384, P=32, R=169
//   out0: patches (B*R, C, P, P) f32 -> 33,226,752 elems
//   out1: pos     (B, R, 2)      f32 -> 21,632 elems (flat after patches)
//
// out[b,r,c,i,j] = bilinear sample of x[b,c,·,·] at
//   row = (j + crop_left[b,r]) * scale   (j = output fast axis)
//   col = (i + crop_top [b,r]) * scale
// scale = 383/384 < 1. Verified R1-R4: 33-row window at floor(crop*scale)
// suffices, always in-bounds, clamp never binds. absmax 0.016 vs thr 7.04.
//
// R5: separable restructure. R2-R4 plateaued at ~40us; DS-pipe arithmetic
// (63KB LDS / 128 DS instrs per block ~ 11-14us/CU) + VALU (~15us) overhang
// the 25us HBM floor. Fix: x-lerp AT LOAD TIME (global -> H in LDS), so the
// compute phase needs 2 taps (1 ds_read2) + 2 fma per output instead of 4
// taps + 6 fma. LDS bytes 63->37KB, DS instrs 128->~75, raw tile eliminated.
#define Bn 64
#define Cn 3
#define Sn 384
#define Pn 32
#define Rn 169
#define HROWS 33                       // y-tap rows: y0 in [0,31], +1 <= 32
#define HPLANE (Pn * HROWS)            // 1056 dwords per channel
#define PATCH_ELEMS (Cn * Pn * Pn)     // 3072
#define POS_OFFSET ((size_t)Bn * Rn * Cn * Pn * Pn)  // 33226752
#define NBLK (Bn * Rn)                 // 10816 = 8 * 1352

typedef float f4 __attribute__((ext_vector_type(4)));

__global__ __launch_bounds__(256) void patch_kernel(
    const float* __restrict__ x,         // (B, C, S, S)
    const int*   __restrict__ crop_top,  // (B, R) -> column axis (i)
    const int*   __restrict__ crop_left, // (B, R) -> row axis (j)
    float*       __restrict__ out)
{
    // XCD-bijective swizzle: 10816 % 8 == 0; consecutive pr share one image
    // for 169 blocks -> image (1.77 MB) L2-resident per XCD.
    const int bid = blockIdx.x;
    const int pr  = (bid & 7) * (NBLK / 8) + (bid >> 3);
    const int b   = pr / Rn;
    const int t   = threadIdx.x;

    // H[c][i][rr]: x-lerped window rows. 3*1056*4 = 12672 B LDS.
    __shared__ float H[Cn * HPLANE];

    const float scale = 383.0f / 384.0f;

    const int ct = crop_top[pr];         // block-uniform
    const int cl = crop_left[pr];
    const float ctf = (float)ct;
    const float clf = (float)cl;
    const int row_base = (int)floorf(clf * scale);

    // ---- Phase 1: H[c][i][rr] = owx*x[r][x0] + wx*x[r][x0+1], from global.
    // Thread (i = t&31, g = t>>5): lanes i consecutive -> the two taps are
    // coalesced ~128B row segments (2 rows per instr across the wave).
    {
        const int i = t & 31;
        const int g = t >> 5;            // 0..7
        float cx  = ((float)i + ctf) * scale;
        float fx  = floorf(cx);
        float wx  = cx - fx;
        float owx = 1.0f - wx;
        int   x0a = (int)fx;             // absolute col, <= 381; +1 <= 382
        const float* xcol = x + (size_t)b * (Cn * Sn * Sn) + x0a;
        float* Hw = H + i * HROWS;
        #pragma unroll
        for (int c = 0; c < Cn; ++c) {
            const float* xc = xcol + c * (Sn * Sn);
            #pragma unroll
            for (int k = 0; k < 5; ++k) {
                int rr = g + 8 * k;      // strided rows; g=0 covers rr=32
                if (rr < HROWS) {
                    const float* p = xc + (row_base + rr) * Sn;
                    float v0 = p[0];
                    float v1 = p[1];
                    // write bank = (33i + rr) % 32 = (i+g+8k)%32 -> 2-way, free
                    Hw[c * HPLANE + rr] = owx * v0 + wx * v1;
                }
            }
        }
    }

    // pos[b,r,0] = crop_top, pos[b,r,1] = crop_left (free slot pre-barrier)
    if (t < 2) {
        out[POS_OFFSET + (size_t)pr * 2 + t] = (t == 0) ? ctf : clf;
    }
    __syncthreads();

    // ---- Phase 2: out(c,i,j) = owy*H[c][i][y0] + wy*H[c][i][y0+1] ----
    // Thread owns (jq = 4*(t&7), i2 = t>>3): per output ONE ds_read2 + 2 fma.
    const int jq = (t & 7) << 2;         // 0,4,...,28
    const int i2 = t >> 3;               // 0..31

    float wyv[4], owyv[4];
    int   yv[4];
    #pragma unroll
    for (int jj = 0; jj < 4; ++jj) {
        float cy = ((float)(jq + jj) + clf) * scale;
        float fy = floorf(cy);
        wyv[jj]  = cy - fy;
        owyv[jj] = 1.0f - wyv[jj];
        yv[jj]   = (int)fy - row_base;   // in [0,31]; +1 <= 32 < HROWS
    }

    float* outp = out + (size_t)pr * PATCH_ELEMS + i2 * Pn + jq;

    #pragma unroll
    for (int c = 0; c < Cn; ++c) {
        const float* Hc = H + c * HPLANE + i2 * HROWS;
        f4 v;
        #pragma unroll
        for (int jj = 0; jj < 4; ++jj) {
            float h0 = Hc[yv[jj]];       // } ds_read2_b32 (offsets 0,1)
            float h1 = Hc[yv[jj] + 1];   // }  bank ~(i2+jq)%32 -> ~2-way, free
            v[jj] = owyv[jj] * h0 + wyv[jj] * h1;
        }
        // wave stores 1KB contiguous, stream-once
        __builtin_nontemporal_store(v, (f4*)(outp + c * (Pn * Pn)));
    }
}

extern "C" void kernel_launch(void* const* d_in, const int* in_sizes, int n_in,
                              void* d_out, int out_size, void* d_ws, size_t ws_size,
                              hipStream_t stream) {
    const float* x         = (const float*)d_in[0];
    const int*   crop_top  = (const int*)d_in[1];
    const int*   crop_left = (const int*)d_in[2];
    float*       out       = (float*)d_out;

    patch_kernel<<<dim3(NBLK), dim3(256), 0, stream>>>(x, crop_top, crop_left, out);
}

// Round 6
// 45.833 us; speedup vs baseline: 1.0898x; 1.0898x over previous
//
#include <hip/hip_runtime.h>

// Problem: B=64, C=3, S=384, P=32, R=169
//   out0: patches (B*R, C, P, P) f32 -> 33,226,752 elems
//   out1: pos     (B, R, 2)      f32 -> 21,632 elems (flat after patches)
//
// out[b,r,c,i,j] = bilinear sample of x[b,c,·,·] at
//   row = (j + crop_left[b,r]) * scale   (j = output fast axis)
//   col = (i + crop_top [b,r]) * scale
// scale = 383/384 < 1. Verified R1-R5: 33-row window at floor(crop*scale)
// suffices, always in-bounds, clamp never binds. absmax 0.016 vs thr 7.04.
//
// R6: persistent blocks + double-buffered pipeline. R3/R4/R5 plateau at
// ~40us vs ~26us HBM floor; all shared one naked global-latency + barrier
// drain per patch-block. Now: 1024 persistent blocks x ~11 patches; per
// iter: prefetch next patch's taps to REGISTERS (flat-issued, fixes R5's
// VGPR=12 serialization) || phase-B of current patch from LDS || lerp+
// ds_write prefetched into other buffer || ONE barrier.
#define Bn 64
#define Cn 3
#define Sn 384
#define Pn 32
#define Rn 169
#define HROWS 33
#define HPLANE (Pn * HROWS)            // 1056 dwords per channel
#define HBUF   (Cn * HPLANE)           // 3168 dwords per buffer
#define PATCH_ELEMS (Cn * Pn * Pn)     // 3072
#define POS_OFFSET ((size_t)Bn * Rn * Cn * Pn * Pn)  // 33226752
#define PER_XCD 1352                   // 10816 / 8
#define SLOTS 128                      // blocks per XCD (grid 1024)

typedef float f4 __attribute__((ext_vector_type(4)));

#define SCALE (383.0f / 384.0f)

// Issue all 30 taps for one patch into registers (flat -> full MLP).
__device__ __forceinline__ void fetch_patch(
    const float* __restrict__ x, const int* __restrict__ crop_top,
    const int* __restrict__ crop_left, int pr, int i, int g,
    float& ctf, float& clf, int& row_base, float& wx, float& owx,
    float v0[15], float v1[15])
{
    int ct = crop_top[pr];              // pr uniform -> s_load
    int cl = crop_left[pr];
    ctf = (float)ct; clf = (float)cl;
    row_base = (int)floorf(clf * SCALE);
    float cx = ((float)i + ctf) * SCALE;
    float fx = floorf(cx);
    wx = cx - fx; owx = 1.0f - wx;
    int x0a = (int)fx;                  // <= 381; +1 <= 382 in-bounds
    int b = pr / Rn;                    // magic-mul (uniform)
    const float* xb = x + (size_t)b * (Cn * Sn * Sn) + x0a;
    int r0 = row_base + 4 * g;          // rows 4g..4g+4 (g=7 -> 28..32=row 32;
                                        // overlap rows double-written, benign)
    #pragma unroll
    for (int c = 0; c < Cn; ++c) {
        #pragma unroll
        for (int k5 = 0; k5 < 5; ++k5) {
            const float* p = xb + c * (Sn * Sn) + (r0 + k5) * Sn;
            v0[c * 5 + k5] = p[0];      // lanes i consecutive -> coalesced
            v1[c * 5 + k5] = p[1];
        }
    }
}

// x-lerp the taps and write H[c][i][rr] (stride 33: write bank (i+4g+k)%32,
// distinct per 32-lane half -> conflict-free; pairs into ds_write2_b32).
__device__ __forceinline__ void lerp_write(
    float* Hb, int i, int g, float wx, float owx,
    const float v0[15], const float v1[15])
{
    float* Hw = Hb + i * HROWS + 4 * g;
    #pragma unroll
    for (int c = 0; c < Cn; ++c) {
        #pragma unroll
        for (int k5 = 0; k5 < 5; ++k5)
            Hw[c * HPLANE + k5] = owx * v0[c * 5 + k5] + wx * v1[c * 5 + k5];
    }
}

// y-lerp from H: one ds_read2 + 2 fma per output. Read bank (i2+y0(jq))%32:
// i2 in 0..3 + y0 ~ 4*jqi -> all 32 lanes distinct banks, conflict-free.
__device__ __forceinline__ void phase_b(
    const float* Hb, float* __restrict__ out, int pr, float clf, int row_base,
    int i2, int jq)
{
    float wyv[4], owyv[4];
    int   yv[4];
    #pragma unroll
    for (int jj = 0; jj < 4; ++jj) {
        float cy = ((float)(jq + jj) + clf) * SCALE;
        float fy = floorf(cy);
        wyv[jj]  = cy - fy;
        owyv[jj] = 1.0f - wyv[jj];
        yv[jj]   = (int)fy - row_base;  // in [0,31]; +1 <= 32 < HROWS
    }
    float* outp = out + (size_t)pr * PATCH_ELEMS + i2 * Pn + jq;
    const float* Hc = Hb + i2 * HROWS;
    #pragma unroll
    for (int c = 0; c < Cn; ++c) {
        f4 v;
        #pragma unroll
        for (int jj = 0; jj < 4; ++jj) {
            float h0 = Hc[c * HPLANE + yv[jj]];      // } ds_read2_b32
            float h1 = Hc[c * HPLANE + yv[jj] + 1];  // } offsets 0,1
            v[jj] = owyv[jj] * h0 + wyv[jj] * h1;
        }
        // wave = 8 i2-groups x 8 jq-lanes x 16B = 1KB contiguous, stream-once
        __builtin_nontemporal_store(v, (f4*)(outp + c * (Pn * Pn)));
    }
}

__global__ __launch_bounds__(256, 4) void patch_kernel(
    const float* __restrict__ x,         // (B, C, S, S)
    const int*   __restrict__ crop_top,  // (B, R) -> column axis (i)
    const int*   __restrict__ crop_left, // (B, R) -> row axis (j)
    float*       __restrict__ out)
{
    __shared__ float H[2 * HBUF];        // 25344 B -> 4 blocks/CU = 101 KB

    const int bid  = blockIdx.x;
    const int xcd  = bid & 7;            // HW round-robin block->XCD
    const int slot = bid >> 3;           // 0..127
    const int t    = threadIdx.x;
    const int i    = t & 31;             // phase-A: column lane
    const int g    = t >> 5;             // phase-A: row group (0..7)
    const int jq   = (t & 7) << 2;       // phase-B: j-quad 0,4,..,28
    const int i2   = t >> 3;             // phase-B: column 0..31
    // slot+128k < 1352: 11 patches for slot<72, else 10
    const int nk   = (slot < 72) ? 11 : 10;

    float v0[15], v1[15];
    float ctf, clf, wx, owx;
    int   row_base;

    int pr = xcd * PER_XCD + slot;
    fetch_patch(x, crop_top, crop_left, pr, i, g, ctf, clf, row_base, wx, owx, v0, v1);
    lerp_write(H, i, g, wx, owx, v0, v1);
    if (t < 2) out[POS_OFFSET + (size_t)pr * 2 + t] = (t == 0) ? ctf : clf;
    __syncthreads();

    float cur_clf = clf;
    int   cur_rb  = row_base;
    int   cur_pr  = pr;

    #pragma unroll 1
    for (int k = 0; k < nk; ++k) {
        const bool pf = (k + 1) < nk;
        int   pr2 = cur_pr + SLOTS;
        float ctf2 = 0.0f, clf2 = 0.0f, wx2 = 0.0f, owx2 = 0.0f;
        int   rb2 = 0;

        // 1) prefetch next patch's taps (global latency hides under phase-B)
        if (pf) fetch_patch(x, crop_top, crop_left, pr2, i, g,
                            ctf2, clf2, rb2, wx2, owx2, v0, v1);

        // 2) compute + store current patch from buf[k&1]
        phase_b(H + (k & 1) * HBUF, out, cur_pr, cur_clf, cur_rb, i2, jq);

        // 3) stage next patch into the OTHER buffer (no WAR with step 2)
        if (pf) {
            lerp_write(H + ((k + 1) & 1) * HBUF, i, g, wx2, owx2, v0, v1);
            if (t < 2) out[POS_OFFSET + (size_t)pr2 * 2 + t] = (t == 0) ? ctf2 : clf2;
        }

        // 4) one barrier per patch: gates buf[(k+1)&1] writes for next iter's
        //    phase-B, and orders this iter's buf[k&1] reads before iter k+1
        //    overwrites it.
        __syncthreads();

        cur_clf = clf2; cur_rb = rb2; cur_pr = pr2;
    }
}

extern "C" void kernel_launch(void* const* d_in, const int* in_sizes, int n_in,
                              void* d_out, int out_size, void* d_ws, size_t ws_size,
                              hipStream_t stream) {
    const float* x         = (const float*)d_in[0];
    const int*   crop_top  = (const int*)d_in[1];
    const int*   crop_left = (const int*)d_in[2];
    float*       out       = (float*)d_out;

    patch_kernel<<<dim3(8 * SLOTS), dim3(256), 0, stream>>>(x, crop_top, crop_left, out);
}

// Round 7
// 37.482 us; speedup vs baseline: 1.3326x; 1.2228x over previous
//
#include <hip/hip_runtime.h>

// Problem: B=64, C=3, S=384, P=32, R=169
//   out0: patches (B*R, C, P, P) f32 -> 33,226,752 elems
//   out1: pos     (B, R, 2)      f32 -> 21,632 elems (flat after patches)
//
// out[b,r,c,i,j] = bilinear sample of x[b,c,·,·] at
//   row = (j + crop_left[b,r]) * scale   (j = output fast axis)
//   col = (i + crop_top [b,r]) * scale
// scale = 383/384 < 1. Verified R1-R6: window rows row_base..row_base+32,
// cols x0a..x0a+1 always in-bounds; clamp never binds. absmax 0.016.
//
// R7 = R4 skeleton (best-known: 1 patch/block, 256thr, XCD swizzle, f4 nt
// stores) + R5's separable x-lerp-at-load (DS instrs ~2x down, 2 fma/output)
// + the fix for R5's real failure (VGPR=12 load serialization): all 24 tap
// loads issued FIRST into named static-indexed registers, lerp+ds_write
// strictly after, no divergent guards in the main load loop.
#define Bn 64
#define Cn 3
#define Sn 384
#define Pn 32
#define Rn 169
#define HROWS 33
#define HPLANE (Pn * HROWS)            // 1056 dwords per channel
#define PATCH_ELEMS (Cn * Pn * Pn)     // 3072
#define POS_OFFSET ((size_t)Bn * Rn * Cn * Pn * Pn)  // 33226752
#define NBLK (Bn * Rn)                 // 10816 = 8 * 1352
#define SCALE (383.0f / 384.0f)

typedef float f4 __attribute__((ext_vector_type(4)));

__global__ __launch_bounds__(256) void patch_kernel(
    const float* __restrict__ x,         // (B, C, S, S)
    const int*   __restrict__ crop_top,  // (B, R) -> column axis (i)
    const int*   __restrict__ crop_left, // (B, R) -> row axis (j)
    float*       __restrict__ out)
{
    // XCD-bijective swizzle (R2-R4: FETCH 48MB, good L2/L3 locality).
    const int bid = blockIdx.x;
    const int pr  = (bid & 7) * (NBLK / 8) + (bid >> 3);
    const int b   = pr / Rn;
    const int t   = threadIdx.x;

    // H[c][i][rr]: x-lerped window rows, stride 33. 12672 B LDS.
    __shared__ float H[Cn * HPLANE];

    const int ct = crop_top[pr];         // block-uniform -> s_load
    const int cl = crop_left[pr];
    const float ctf = (float)ct, clf = (float)cl;
    const int row_base = (int)floorf(clf * SCALE);

    // ---- Phase A: tap loads -> registers (24-deep MLP), then lerp -> LDS
    // Thread (i = t&31, g = t>>5) owns column i, rows 4g..4g+3.
    const int i = t & 31;
    const int g = t >> 5;
    float cx  = ((float)i + ctf) * SCALE;
    float fx  = floorf(cx);
    float wx  = cx - fx;
    float owx = 1.0f - wx;
    // x0a = (int)fx <= 382; +1 <= 383 in-bounds. Lanes i consecutive ->
    // x0a consecutive-ish -> each load instr is a coalesced ~128B segment.
    const float* basep = x + (size_t)b * (Cn * Sn * Sn) + (int)fx;
    const float* rp    = basep + (row_base + 4 * g) * Sn;

    // 1) issue all 24 loads into named registers (static indices -> VGPRs)
    float a0[Cn][4], a1[Cn][4];
    #pragma unroll
    for (int c = 0; c < Cn; ++c) {
        const float* p = rp + c * (Sn * Sn);
        #pragma unroll
        for (int k = 0; k < 4; ++k) {
            a0[c][k] = p[k * Sn];        // global_load_dword, imm offsets
            a1[c][k] = p[k * Sn + 1];
        }
    }
    // row 32 extra taps: threads 0..31 (divergent in wave 0 only; 6 loads)
    float e0[Cn], e1[Cn];
    if (t < 32) {
        const float* p = basep + (row_base + 32) * Sn;
        #pragma unroll
        for (int c = 0; c < Cn; ++c) {
            e0[c] = p[c * (Sn * Sn)];
            e1[c] = p[c * (Sn * Sn) + 1];
        }
    }
    // pos output rides in the load shadow
    if (t < 2) out[POS_OFFSET + (size_t)pr * 2 + t] = (t == 0) ? ctf : clf;

    // 2) x-lerp + LDS write, strictly after all loads are in flight.
    // Write bank = (33i + 4g + k)%32 = (i+4g+k)%32 -> exactly 2 lanes/bank
    // (free, m136); k=0..3 consecutive dwords -> 2x ds_write2_b32 per c.
    float* Hw = H + i * HROWS + 4 * g;
    #pragma unroll
    for (int c = 0; c < Cn; ++c) {
        #pragma unroll
        for (int k = 0; k < 4; ++k)
            Hw[c * HPLANE + k] = owx * a0[c][k] + wx * a1[c][k];
    }
    if (t < 32) {
        #pragma unroll
        for (int c = 0; c < Cn; ++c)
            H[c * HPLANE + t * HROWS + 32] = owx * e0[c] + wx * e1[c];
    }
    __syncthreads();

    // ---- Phase B: out(c,i,j) = owy*H[c][i][y0] + wy*H[c][i][y0+1] ----
    // Thread (jq = 4*(t&7), i2 = t>>3): ONE ds_read2 + 2 fma per output.
    // Read bank = (i2 + y0(jq+jj))%32 ~ (i2 + 4*(t&7))%32 -> 2 lanes/bank, free.
    const int jq = (t & 7) << 2;
    const int i2 = t >> 3;

    float wyv[4], owyv[4];
    int   yv[4];
    #pragma unroll
    for (int jj = 0; jj < 4; ++jj) {
        float cy = ((float)(jq + jj) + clf) * SCALE;
        float fy = floorf(cy);
        wyv[jj]  = cy - fy;
        owyv[jj] = 1.0f - wyv[jj];
        yv[jj]   = (int)fy - row_base;   // in [0,31]; +1 <= 32 < HROWS
    }

    float* outp = out + (size_t)pr * PATCH_ELEMS + i2 * Pn + jq;

    #pragma unroll
    for (int c = 0; c < Cn; ++c) {
        const float* Hc = H + c * HPLANE + i2 * HROWS;
        f4 v;
        #pragma unroll
        for (int jj = 0; jj < 4; ++jj) {
            float h0 = Hc[yv[jj]];       // } ds_read2_b32 (offsets 0,1)
            float h1 = Hc[yv[jj] + 1];   // }
            v[jj] = owyv[jj] * h0 + wyv[jj] * h1;
        }
        // wave = 8 i2-groups x 8 jq-lanes x 16B = 1KB contiguous, stream-once
        __builtin_nontemporal_store(v, (f4*)(outp + c * (Pn * Pn)));
    }
}

extern "C" void kernel_launch(void* const* d_in, const int* in_sizes, int n_in,
                              void* d_out, int out_size, void* d_ws, size_t ws_size,
                              hipStream_t stream) {
    const float* x         = (const float*)d_in[0];
    const int*   crop_top  = (const int*)d_in[1];
    const int*   crop_left = (const int*)d_in[2];
    float*       out       = (float*)d_out;

    patch_kernel<<<dim3(NBLK), dim3(256), 0, stream>>>(x, crop_top, crop_left, out);
}